// Round 2
// baseline (283.391 us; speedup 1.0000x reference)
//
#include <hip/hip_runtime.h>
#include <math.h>

// B=4096 rows, C=8192 cols, f32. Scalar = mean over (row, positive) pairs of
// log1p(exp(lse_neg(row) - x_p)). weights input unused (cancels).
//
// Single-pass design: each block owns one row. Threads stream the row once
// with a branchless online softmax (m, s) update; positives (~8/row) are
// appended to an LDS list via LDS atomics. lse over negatives is recovered by
// subtracting the positives' exp contribution from the all-elements sum.

#define ROWS 4096
#define COLS 8192
#define TPB  256
#define VEC_ITERS (COLS / (TPB * 4))   // 8 float4 iters per thread
#define MAX_POS 1024                   // positives/row bound (~8 expected)

__device__ __forceinline__ void onlineMerge(float& m, float& s,
                                            float mo, float so) {
    float M = fmaxf(m, mo);
    s = s * __expf(m - M) + so * __expf(mo - M);
    m = M;
}

__global__ __launch_bounds__(TPB) void row_loss_kernel(
        const float* __restrict__ logits,
        const float* __restrict__ target,
        float* __restrict__ ws_loss,
        float* __restrict__ ws_cnt) {
    const int row = blockIdx.x;
    const int tid = threadIdx.x;
    const int wave = tid >> 6;

    __shared__ int   npos;
    __shared__ float posv[MAX_POS];
    __shared__ float sm[4], ss[4];

    if (tid == 0) npos = 0;
    __syncthreads();

    const float4* __restrict__ orow =
        (const float4*)(logits + (size_t)row * COLS);
    const float4* __restrict__ trow =
        (const float4*)(target + (size_t)row * COLS);

    // --- Single pass: online (m, s) over ALL elements + collect positives ---
    float m = -3.0e38f, s = 0.f;
#pragma unroll
    for (int i = 0; i < VEC_ITERS; i++) {
        float4 o = orow[tid + i * TPB];
        float4 t = trow[tid + i * TPB];
        float mq = fmaxf(fmaxf(o.x, o.y), fmaxf(o.z, o.w));
        float M = fmaxf(m, mq);
        s = s * __expf(m - M)
          + __expf(o.x - M) + __expf(o.y - M)
          + __expf(o.z - M) + __expf(o.w - M);
        m = M;
        if (t.x != 0.f) { int p = atomicAdd(&npos, 1); if (p < MAX_POS) posv[p] = o.x; }
        if (t.y != 0.f) { int p = atomicAdd(&npos, 1); if (p < MAX_POS) posv[p] = o.y; }
        if (t.z != 0.f) { int p = atomicAdd(&npos, 1); if (p < MAX_POS) posv[p] = o.z; }
        if (t.w != 0.f) { int p = atomicAdd(&npos, 1); if (p < MAX_POS) posv[p] = o.w; }
    }

    // --- Wave-level online merge of (m, s) ---
#pragma unroll
    for (int off = 32; off > 0; off >>= 1) {
        float mo = __shfl_xor(m, off, 64);
        float so = __shfl_xor(s, off, 64);
        onlineMerge(m, s, mo, so);
    }
    if ((tid & 63) == 0) { sm[wave] = m; ss[wave] = s; }
    __syncthreads();

    // Every thread redundantly merges the 4 wave partials.
    float M = sm[0], S = ss[0];
    onlineMerge(M, S, sm[1], ss[1]);
    onlineMerge(M, S, sm[2], ss[2]);
    onlineMerge(M, S, sm[3], ss[3]);

    const int np = min(npos, MAX_POS);

    // --- Subtract positives' exp contribution: S_neg = S_all - sum_p e^(x_p-M)
    float es = 0.f;
    for (int i = tid; i < np; i += TPB) es += __expf(posv[i] - M);
#pragma unroll
    for (int off = 32; off > 0; off >>= 1) es += __shfl_xor(es, off, 64);
    if ((tid & 63) == 0) ss[wave] = es;
    __syncthreads();
    const float es_tot = ss[0] + ss[1] + ss[2] + ss[3];
    const float lse_neg = M + __logf(S - es_tot);
    __syncthreads();

    // --- Loss over positives ---
    float loss = 0.f;
    for (int i = tid; i < np; i += TPB)
        loss += log1pf(__expf(lse_neg - posv[i]));
#pragma unroll
    for (int off = 32; off > 0; off >>= 1) loss += __shfl_xor(loss, off, 64);
    if ((tid & 63) == 0) ss[wave] = loss;
    __syncthreads();
    if (tid == 0) {
        ws_loss[row] = ss[0] + ss[1] + ss[2] + ss[3];
        ws_cnt[row]  = (float)np;
    }
}

__global__ __launch_bounds__(TPB) void finalize_kernel(
        const float* __restrict__ ws_loss,
        const float* __restrict__ ws_cnt,
        float* __restrict__ out) {
    const int tid = threadIdx.x;
    float l = 0.f, c = 0.f;
    for (int i = tid; i < ROWS; i += TPB) {
        l += ws_loss[i];
        c += ws_cnt[i];
    }
#pragma unroll
    for (int off = 32; off > 0; off >>= 1) {
        l += __shfl_xor(l, off, 64);
        c += __shfl_xor(c, off, 64);
    }
    __shared__ float sl[4], sc[4];
    if ((tid & 63) == 0) { sl[tid >> 6] = l; sc[tid >> 6] = c; }
    __syncthreads();
    if (tid == 0) {
        float L = sl[0] + sl[1] + sl[2] + sl[3];
        float N = sc[0] + sc[1] + sc[2] + sc[3];
        out[0] = L / N;
    }
}

extern "C" void kernel_launch(void* const* d_in, const int* in_sizes, int n_in,
                              void* d_out, int out_size, void* d_ws, size_t ws_size,
                              hipStream_t stream) {
    const float* logits = (const float*)d_in[0];   // [B, C]
    const float* target = (const float*)d_in[1];   // [B, C]
    // d_in[2] (weights) unused: per-sample CE weight cancels.
    float* ws_loss = (float*)d_ws;                 // [ROWS]
    float* ws_cnt  = ws_loss + ROWS;               // [ROWS]

    row_loss_kernel<<<ROWS, TPB, 0, stream>>>(logits, target, ws_loss, ws_cnt);
    finalize_kernel<<<1, TPB, 0, stream>>>(ws_loss, ws_cnt, (float*)d_out);
}